// Round 1
// baseline (91.545 us; speedup 1.0000x reference)
//
#include <hip/hip_runtime.h>
#include <cstdint>

// I-BERT IntSoftmax, single pass.
// Exactness notes:
//  - All "integer" intermediates (x_int, q, r, z, exp_int, exp_q, row sums)
//    are integers exactly representable in f32 (partial sums < 2^24), so any
//    summation/fma ordering is exact and matches the reference bit-for-bit.
//  - All non-exact ops (divisions, the eq*factor product) are single IEEE f32
//    ops in the same order as the reference.
//  - Global max of exp_int is analytically c_int * 2^30 (attained at the
//    row-argmax element of every row; all other elements are <= it since
//    r*(r+b_int) <= 0 and 2^(30-q) <= 2^30 with exact products). This removes
//    the device-wide QuantAct reduction -> single-pass kernel.

static __device__ __forceinline__ float wave_max(float v) {
#pragma unroll
    for (int m = 32; m >= 1; m >>= 1) v = fmaxf(v, __shfl_xor(v, m, 64));
    return v;
}
static __device__ __forceinline__ float wave_sum(float v) {
#pragma unroll
    for (int m = 32; m >= 1; m >>= 1) v += __shfl_xor(v, m, 64);
    return v;
}

__global__ __launch_bounds__(256) void intsoftmax_ibert_kernel(
    const float* __restrict__ x, const float* __restrict__ sfp,
    float* __restrict__ out, long long n_total)
{
    const float sfv = sfp[0];

    // Wave-uniform constants (match JAX f32 semantics: python-float consts are
    // rounded to f32 first, then one IEEE f32 division).
    const float x0i = floorf(-0.6931f / sfv);                          // x0_int (negative)
    const float bi  = floorf((float)(0.96963238 / 0.35815147) / sfv);  // b_int
    const float ci  = floorf((float)(1.0 / 0.35815147) / (sfv * sfv)); // c_int
    const float lo  = 30.0f * x0i;                                     // N_SHIFT * x0_int
    // Global exp_int max = ci * 2^30 (exact: integer * power of two).
    const float act_scale = (ci * 1073741824.0f) / 32767.0f;           // max_abs / ACT_QMAX

    const int lane = threadIdx.x & 63;
    const int wv   = threadIdx.x >> 6;
    const long long row = (long long)blockIdx.x * 4 + wv;

    const float4* __restrict__ xr   = (const float4*)(x + row * 1024);
    float4* __restrict__       orow = (float4*)(out + row * 1024);

    // Load 16 elements/lane (4 x float4, coalesced: lane + 64*k).
    float xi[16];
#pragma unroll
    for (int k = 0; k < 4; ++k) {
        float4 a = xr[lane + 64 * k];
        xi[4 * k + 0] = truncf(a.x / sfv);
        xi[4 * k + 1] = truncf(a.y / sfv);
        xi[4 * k + 2] = truncf(a.z / sfv);
        xi[4 * k + 3] = truncf(a.w / sfv);
    }

    // Row max of x_int.
    float m = xi[0];
#pragma unroll
    for (int i = 1; i < 16; ++i) m = fmaxf(m, xi[i]);
    m = wave_max(m);

    // int_exp + QuantAct(16) requantization.
    float eq[16];
    float lsum = 0.0f;
#pragma unroll
    for (int i = 0; i < 16; ++i) {
        float v = fmaxf(xi[i] - m, lo);        // clamp to N_SHIFT * x0_int
        float q = floorf(v / x0i);             // 0..30 (IEEE div; operands are
                                               // small ints -> floor is safe)
        float r = v - x0i * q;                 // exact integer
        float z = r * (r + bi) + ci;           // exact integer < 2^24
        int  qi = (int)q;
        float p2 = __uint_as_float((uint32_t)(157 - qi) << 23); // exact 2^(30-q)
        float e  = fmaxf(floorf(z * p2), 0.0f);                 // exp_int (exact product)
        float t  = rintf(e / act_scale);       // jnp.round = half-to-even = rintf
        t = fminf(fmaxf(t, -32767.0f), 32767.0f);
        eq[i] = t;
        lsum += t;                             // partials < 2^24 -> exact
    }
    float s = wave_sum(lsum);                  // exact integer sum
    float factor = floorf(4294967296.0f / s);  // floor(2^32 / sum), IEEE div

    // out = floor(exp_q * factor / 2^25) * (2 / 2^8)
#pragma unroll
    for (int k = 0; k < 4; ++k) {
        float4 o;
        o.x = floorf(eq[4 * k + 0] * factor * (1.0f / 33554432.0f)) * 0.0078125f;
        o.y = floorf(eq[4 * k + 1] * factor * (1.0f / 33554432.0f)) * 0.0078125f;
        o.z = floorf(eq[4 * k + 2] * factor * (1.0f / 33554432.0f)) * 0.0078125f;
        o.w = floorf(eq[4 * k + 3] * factor * (1.0f / 33554432.0f)) * 0.0078125f;
        orow[lane + 64 * k] = o;
    }

    // Second tuple output: out_scale scalar appended at the end.
    if (blockIdx.x == 0 && threadIdx.x == 0) out[n_total] = 0.0078125f;
}

extern "C" void kernel_launch(void* const* d_in, const int* in_sizes, int n_in,
                              void* d_out, int out_size, void* d_ws, size_t ws_size,
                              hipStream_t stream) {
    const float* x  = (const float*)d_in[0];
    const float* sf = (const float*)d_in[1];
    float* out = (float*)d_out;

    const long long n_total = (long long)out_size - 1;   // 4*12*1024*1024
    const int rows = (int)(n_total / 1024);              // 49152
    const int grid = rows / 4;                           // 4 rows (waves) per 256-thr block

    intsoftmax_ibert_kernel<<<grid, 256, 0, stream>>>(x, sf, out, n_total);
}

// Round 3
// 54.937 us; speedup vs baseline: 1.6664x; 1.6664x over previous
//
#include <hip/hip_runtime.h>
#include <cstdint>

// I-BERT IntSoftmax, single pass, division-free inner loop.
//
// Exactness argument (all must match JAX/numpy f32 bit-for-bit; threshold
// 1.875e-3 < out_scale 0.0078125 so every out_int must be exact):
//  - Global QuantAct max over exp_int is analytically ci*2^30 (attained at each
//    row argmax: q=0,r=0,z=ci; all other elements <= since r*(r+bi)<=0 and
//    2^(30-q)<=2^30, all products exact) -> no device-wide reduction needed.
//  - x/sfv and e/act_scale: divisors are wave-uniform. With y = RN(1/b)
//    (computed once via double, correctly rounded), Markstein's single
//    correction q0=a*y; r=fma(-b,q0,a); fma(r,y,q0) yields the correctly
//    rounded IEEE f32 quotient -> identical bits to v_div.
//  - floor(v/x0i): v,x0i exact integers; non-multiple quotients are >=1/x0a
//    away from integers; rpu = 1-ulp-up of RN(1/x0a) gives vp*rpu in
//    [true, true+~30*2^-22] -> floorf exact.
//  - z (= r*(r+bi)+ci) is a positive integer < 2^24 and 2^(30-q) is an exact
//    power of two (q in [0,30]) -> floor/max(.,0) on exp_int are no-ops.
//  - Integer intermediates (x_int,q,r,z,exp_q,partial sums<2^24) are exact in
//    f32, so summation order is irrelevant.

typedef float floatx4 __attribute__((ext_vector_type(4)));  // native vec for nt-store

static __device__ __forceinline__ float wave_max(float v) {
#pragma unroll
    for (int m = 32; m >= 1; m >>= 1) v = fmaxf(v, __shfl_xor(v, m, 64));
    return v;
}
static __device__ __forceinline__ float wave_sum(float v) {
#pragma unroll
    for (int m = 32; m >= 1; m >>= 1) v += __shfl_xor(v, m, 64);
    return v;
}

// Correctly-rounded a/b given y = RN(1/b)  (Markstein final-correction).
static __device__ __forceinline__ float div_cr(float a, float b, float y) {
    float q0 = a * y;
    float r0 = fmaf(-b, q0, a);
    return fmaf(r0, y, q0);
}

__global__ __launch_bounds__(256) void intsoftmax_ibert_kernel(
    const float* __restrict__ x, const float* __restrict__ sfp,
    float* __restrict__ out, long long n_total)
{
    const float sfv = sfp[0];

    // Wave-uniform preamble (real divs here are once-per-wave).
    const float x0i = floorf(-0.6931f / sfv);                          // x0_int < 0
    const float bi  = floorf((float)(0.96963238 / 0.35815147) / sfv);  // b_int
    const float ci  = floorf((float)(1.0 / 0.35815147) / (sfv * sfv)); // c_int
    const float x0a = -x0i;                                            // |x0_int|
    const float hi  = 30.0f * x0a;                                     // clamp (positive form)
    const float as  = (ci * 1073741824.0f) / 32767.0f;                 // act_scale (IEEE div)

    const float ysf = (float)(1.0 / (double)sfv);   // RN(1/sfv)
    const float yas = (float)(1.0 / (double)as);    // RN(1/act_scale)
    const float rpu = __uint_as_float(__float_as_uint((float)(1.0 / (double)x0a)) + 1); // >= 1/x0a

    const int lane = threadIdx.x & 63;
    const int wv   = threadIdx.x >> 6;
    const long long row = (long long)blockIdx.x * 4 + wv;

    const floatx4* __restrict__ xr   = (const floatx4*)(x + row * 1024);
    floatx4* __restrict__       orow = (floatx4*)(out + row * 1024);

    // x_int = trunc(x / sf), 16 elements/lane, coalesced 16B loads.
    float xi[16];
#pragma unroll
    for (int k = 0; k < 4; ++k) {
        floatx4 a = xr[lane + 64 * k];
#pragma unroll
        for (int j = 0; j < 4; ++j)
            xi[4 * k + j] = truncf(div_cr(a[j], sfv, ysf));
    }

    float m = xi[0];
#pragma unroll
    for (int i = 1; i < 16; ++i) m = fmaxf(m, xi[i]);
    m = wave_max(m);

    // int_exp + QuantAct(16) requant (exp_q), all exact-integer arithmetic.
    float eq[16];
    float lsum = 0.0f;
#pragma unroll
    for (int i = 0; i < 16; ++i) {
        float vp = fminf(m - xi[i], hi);              // = -v, in [0, 30*x0a]
        float q  = floorf(vp * rpu);                  // exact floor(v/x0i), 0..30
        float r  = fmaf(x0a, q, -vp);                 // = v - x0i*q, exact int in (-x0a, 0]
        float z  = fmaf(r, r + bi, ci);               // exact int, 0 < z < 2^24
        float p2 = __uint_as_float((uint32_t)(157 - (int)q) << 23); // 2^(30-q)
        float e  = z * p2;                            // exp_int, exact
        float t  = rintf(div_cr(e, as, yas));         // round-half-even, IEEE-exact
        t = fminf(t, 32767.0f);                       // clip (t >= 0 always)
        eq[i] = t;
        lsum += t;                                    // partials < 2^24 -> exact
    }
    float s = wave_sum(lsum);
    float factor = floorf(4294967296.0f / s);         // once per row: keep real div

    // out_int = floor(exp_q * factor / 2^25); out = out_int * 2^-7
#pragma unroll
    for (int k = 0; k < 4; ++k) {
        floatx4 o;
#pragma unroll
        for (int j = 0; j < 4; ++j)
            o[j] = floorf(eq[4 * k + j] * factor * (1.0f / 33554432.0f)) * 0.0078125f;
        __builtin_nontemporal_store(o, &orow[lane + 64 * k]);  // streaming store
    }

    if (blockIdx.x == 0 && threadIdx.x == 0) out[n_total] = 0.0078125f;
}

extern "C" void kernel_launch(void* const* d_in, const int* in_sizes, int n_in,
                              void* d_out, int out_size, void* d_ws, size_t ws_size,
                              hipStream_t stream) {
    const float* x  = (const float*)d_in[0];
    const float* sf = (const float*)d_in[1];
    float* out = (float*)d_out;

    const long long n_total = (long long)out_size - 1;   // 4*12*1024*1024
    const int rows = (int)(n_total / 1024);              // 49152
    const int grid = rows / 4;                           // 4 waves (rows) per block

    intsoftmax_ibert_kernel<<<grid, 256, 0, stream>>>(x, sf, out, n_total);
}